// Round 1
// baseline (227.275 us; speedup 1.0000x reference)
//
#include <hip/hip_runtime.h>
#include <math.h>

// Problem constants (fixed by setup_inputs)
constexpr int B = 256, S = 1024, D = 32, K = 512;
constexpr float LOG2E   = 1.4426950408889634f;
constexpr float LN2     = 0.6931471805599453f;
constexpr float LOG_NORM = 29.40603306051f; // D * (log(STD)=0 + 0.5*log(2*pi))

#if __has_builtin(__builtin_amdgcn_exp2f)
#define EXP2F(v) __builtin_amdgcn_exp2f(v)
#else
#define EXP2F(v) exp2f(v)
#endif
#if __has_builtin(__builtin_amdgcn_logf)
#define LOG2F(v) __builtin_amdgcn_logf(v)
#else
#define LOG2F(v) log2f(v)
#endif

// Grid: B*2 blocks of 256 threads. Block handles batch b = blockIdx>>1,
// s-range [ (blockIdx&1)*512, +512 ). Each thread computes 2 output points
// (s0 and s0+256) -> 2 independent FMA chains for ILP.
__global__ __launch_bounds__(256)
void gm_nll_kernel(const float* __restrict__ x,
                   const float* __restrict__ logits,
                   const float* __restrict__ means,
                   float* __restrict__ out)
{
    __shared__ float a2s[K];   // (logit - lse - 0.5*m2[k]) * log2(e)
    __shared__ float red[8];

    const int tid  = threadIdx.x;
    const int lane = tid & 63;
    const int wid  = tid >> 6;
    const int b     = blockIdx.x >> 1;
    const int sbase = (blockIdx.x & 1) * 512;

    // ---- per-batch prep: logsumexp over logits[b, :] (K=512, 2 per thread) ----
    const float l0 = logits[b * K + tid];
    const float l1 = logits[b * K + tid + 256];

    float mx = fmaxf(l0, l1);
    #pragma unroll
    for (int off = 32; off >= 1; off >>= 1)
        mx = fmaxf(mx, __shfl_xor(mx, off));
    if (lane == 0) red[wid] = mx;
    __syncthreads();
    mx = fmaxf(fmaxf(red[0], red[1]), fmaxf(red[2], red[3]));

    float sum = EXP2F((l0 - mx) * LOG2E) + EXP2F((l1 - mx) * LOG2E);
    #pragma unroll
    for (int off = 32; off >= 1; off >>= 1)
        sum += __shfl_xor(sum, off);
    if (lane == 0) red[4 + wid] = sum;
    __syncthreads();
    sum = red[4] + red[5] + red[6] + red[7];
    const float lse = mx + LN2 * LOG2F(sum);

    // ---- a2s[k] = (logit[k] - lse - 0.5*||mu_k||^2) * log2(e) ----
    {
        const float4* mrow = (const float4*)means + (size_t)tid * 8;
        float m2 = 0.f;
        #pragma unroll
        for (int i = 0; i < 8; ++i) {
            float4 v = mrow[i];
            m2 += v.x * v.x + v.y * v.y + v.z * v.z + v.w * v.w;
        }
        a2s[tid] = (l0 - lse - 0.5f * m2) * LOG2E;

        mrow = (const float4*)means + (size_t)(tid + 256) * 8;
        m2 = 0.f;
        #pragma unroll
        for (int i = 0; i < 8; ++i) {
            float4 v = mrow[i];
            m2 += v.x * v.x + v.y * v.y + v.z * v.z + v.w * v.w;
        }
        a2s[tid + 256] = (l1 - lse - 0.5f * m2) * LOG2E;
    }
    __syncthreads();

    // ---- load x for the two points; keep x pre-scaled by log2(e) ----
    const int s0 = sbase + tid;                 // second point: s0 + 256
    const float4* xp0 = (const float4*)(x + ((size_t)b * S + s0) * D);
    const float4* xp1 = (const float4*)(x + ((size_t)b * S + s0 + 256) * D);

    float xs0[D], xs1[D];
    float x2_0 = 0.f, x2_1 = 0.f;
    #pragma unroll
    for (int i = 0; i < 8; ++i) {
        float4 v = xp0[i];
        x2_0 += v.x * v.x + v.y * v.y + v.z * v.z + v.w * v.w;
        xs0[4 * i + 0] = v.x * LOG2E; xs0[4 * i + 1] = v.y * LOG2E;
        xs0[4 * i + 2] = v.z * LOG2E; xs0[4 * i + 3] = v.w * LOG2E;
        float4 w = xp1[i];
        x2_1 += w.x * w.x + w.y * w.y + w.z * w.z + w.w * w.w;
        xs1[4 * i + 0] = w.x * LOG2E; xs1[4 * i + 1] = w.y * LOG2E;
        xs1[4 * i + 2] = w.z * LOG2E; xs1[4 * i + 3] = w.w * LOG2E;
    }

    // ---- main loop over K components ----
    float acc0 = 0.f, acc1 = 0.f;
    const float4* mp = (const float4*)means;
    #pragma unroll 2
    for (int k = 0; k < K; ++k) {
        float d0 = 0.f, d1 = 0.f;
        #pragma unroll
        for (int i = 0; i < 8; ++i) {
            float4 mv = mp[(size_t)k * 8 + i];   // wave-broadcast load, L1/L2-hot
            d0 = fmaf(xs0[4 * i + 0], mv.x, d0);
            d0 = fmaf(xs0[4 * i + 1], mv.y, d0);
            d0 = fmaf(xs0[4 * i + 2], mv.z, d0);
            d0 = fmaf(xs0[4 * i + 3], mv.w, d0);
            d1 = fmaf(xs1[4 * i + 0], mv.x, d1);
            d1 = fmaf(xs1[4 * i + 1], mv.y, d1);
            d1 = fmaf(xs1[4 * i + 2], mv.z, d1);
            d1 = fmaf(xs1[4 * i + 3], mv.w, d1);
        }
        const float a2 = a2s[k];
        acc0 += EXP2F(a2 + d0);
        acc1 += EXP2F(a2 + d1);
    }

    out[(size_t)b * S + s0]       = 0.5f * x2_0 + LOG_NORM - LN2 * LOG2F(acc0);
    out[(size_t)b * S + s0 + 256] = 0.5f * x2_1 + LOG_NORM - LN2 * LOG2F(acc1);
}

extern "C" void kernel_launch(void* const* d_in, const int* in_sizes, int n_in,
                              void* d_out, int out_size, void* d_ws, size_t ws_size,
                              hipStream_t stream) {
    const float* x      = (const float*)d_in[0];
    const float* logits = (const float*)d_in[1];
    const float* means  = (const float*)d_in[2];
    float* out = (float*)d_out;
    (void)in_sizes; (void)n_in; (void)out_size; (void)d_ws; (void)ws_size;

    dim3 grid(B * 2), block(256);
    hipLaunchKernelGGL(gm_nll_kernel, grid, block, 0, stream, x, logits, means, out);
}

// Round 2
// 100.235 us; speedup vs baseline: 2.2674x; 2.2674x over previous
//
#include <hip/hip_runtime.h>
#include <math.h>

// Problem constants (fixed by setup_inputs)
constexpr int Bc = 256, Sc = 1024, Dc = 32, Kc = 512;
constexpr int ST = 128;                      // s-rows per block
constexpr float LOG2E    = 1.4426950408889634f;
constexpr float LN2      = 0.6931471805599453f;
constexpr float LOG_NORM = 29.40603306051f;  // D * (log(STD)=0 + 0.5*log(2*pi))

typedef __attribute__((ext_vector_type(8))) short          bf16x8;
typedef __attribute__((ext_vector_type(8))) unsigned short u16x8;
typedef __attribute__((ext_vector_type(4))) float          f32x4;

#if __has_builtin(__builtin_amdgcn_exp2f)
#define EXP2F(v) __builtin_amdgcn_exp2f(v)
#else
#define EXP2F(v) exp2f(v)
#endif
#if __has_builtin(__builtin_amdgcn_logf)
#define LOG2F(v) __builtin_amdgcn_logf(v)
#else
#define LOG2F(v) log2f(v)
#endif

__device__ __forceinline__ unsigned short f2bf(float f) {
    unsigned u = __float_as_uint(f);
    u += 0x7fff + ((u >> 16) & 1);           // round-to-nearest-even
    return (unsigned short)(u >> 16);
}

// XOR-swizzled LDS offset (ushort units): row stride 32 bf16 (64B),
// chunk = 16B octet index 0..3, swizzled by (row>>1)&3 to balance banks.
__device__ __forceinline__ int swz(int row, int chunk) {
    return row * 32 + ((chunk ^ ((row >> 1) & 3)) << 3);
}

__global__ __launch_bounds__(256)
void gm_nll_mfma(const float* __restrict__ x, const float* __restrict__ logits,
                 const float* __restrict__ means, float* __restrict__ out)
{
    __shared__ unsigned short mlds[Kc * 32];  // 32 KB: bf16 means, row-major
    __shared__ unsigned short xlds[ST * 32];  //  8 KB: bf16 (x * log2e)
    __shared__ float a2s[Kc];                 // (logit - lse - 0.5*m2)*log2e
    __shared__ float x2p[256];                // per-half-row sum(x^2)
    __shared__ float red[8];

    const int tid  = threadIdx.x;
    const int lane = tid & 63;
    const int wid  = tid >> 6;
    const int b    = blockIdx.x >> 3;         // 8 s-tiles per batch
    const int s0   = (blockIdx.x & 7) * ST;

    // ---- logsumexp over logits[b,:]; thread owns k = 2t, 2t+1 ----
    const float l0 = logits[b * Kc + 2 * tid];
    const float l1 = logits[b * Kc + 2 * tid + 1];
    float mx = fmaxf(l0, l1);
    #pragma unroll
    for (int off = 32; off >= 1; off >>= 1) mx = fmaxf(mx, __shfl_xor(mx, off));
    if (lane == 0) red[wid] = mx;
    __syncthreads();
    mx = fmaxf(fmaxf(red[0], red[1]), fmaxf(red[2], red[3]));
    float sm = EXP2F((l0 - mx) * LOG2E) + EXP2F((l1 - mx) * LOG2E);
    #pragma unroll
    for (int off = 32; off >= 1; off >>= 1) sm += __shfl_xor(sm, off);
    if (lane == 0) red[4 + wid] = sm;
    __syncthreads();
    sm = red[4] + red[5] + red[6] + red[7];
    const float lse = mx + LN2 * LOG2F(sm);

    // ---- means -> bf16 LDS + m2 + a2s; thread t owns rows 2t, 2t+1 ----
    {
        const float4* mp4 = (const float4*)means + (size_t)tid * 16;
        #pragma unroll
        for (int rr = 0; rr < 2; ++rr) {
            const int row = 2 * tid + rr;
            float m2 = 0.f;
            #pragma unroll
            for (int c = 0; c < 4; ++c) {
                float4 v0 = mp4[rr * 8 + 2 * c];
                float4 v1 = mp4[rr * 8 + 2 * c + 1];
                m2 += v0.x*v0.x + v0.y*v0.y + v0.z*v0.z + v0.w*v0.w
                    + v1.x*v1.x + v1.y*v1.y + v1.z*v1.z + v1.w*v1.w;
                u16x8 pk;
                pk[0]=f2bf(v0.x); pk[1]=f2bf(v0.y); pk[2]=f2bf(v0.z); pk[3]=f2bf(v0.w);
                pk[4]=f2bf(v1.x); pk[5]=f2bf(v1.y); pk[6]=f2bf(v1.z); pk[7]=f2bf(v1.w);
                *(u16x8*)&mlds[swz(row, c)] = pk;
            }
            const float lg = (rr == 0) ? l0 : l1;
            a2s[row] = (lg - lse - 0.5f * m2) * LOG2E;
        }
    }

    // ---- x tile -> bf16*log2e LDS + x2 partials; thread owns row t>>1, half t&1 ----
    {
        const int row = tid >> 1, h = tid & 1;
        const float4* xp4 = (const float4*)(x + ((size_t)b * Sc + s0 + row) * Dc) + h * 4;
        float s2 = 0.f;
        #pragma unroll
        for (int j = 0; j < 2; ++j) {
            float4 v0 = xp4[2 * j];
            float4 v1 = xp4[2 * j + 1];
            s2 += v0.x*v0.x + v0.y*v0.y + v0.z*v0.z + v0.w*v0.w
                + v1.x*v1.x + v1.y*v1.y + v1.z*v1.z + v1.w*v1.w;
            u16x8 pk;
            pk[0]=f2bf(v0.x*LOG2E); pk[1]=f2bf(v0.y*LOG2E);
            pk[2]=f2bf(v0.z*LOG2E); pk[3]=f2bf(v0.w*LOG2E);
            pk[4]=f2bf(v1.x*LOG2E); pk[5]=f2bf(v1.y*LOG2E);
            pk[6]=f2bf(v1.z*LOG2E); pk[7]=f2bf(v1.w*LOG2E);
            *(u16x8*)&xlds[swz(row, 2 * h + j)] = pk;
        }
        x2p[tid] = s2;
    }
    __syncthreads();

    // ---- main loop: wave owns 32 s-rows (two 16-row subtiles) ----
    const int q  = lane >> 4;     // quad -> k-octet of the contraction dim
    const int ln = lane & 15;
    const int rw = wid * 32;

    const bf16x8 a0 = *(const bf16x8*)&xlds[swz(rw + ln, q)];
    const bf16x8 a1 = *(const bf16x8*)&xlds[swz(rw + 16 + ln, q)];

    float acc0[4] = {0.f, 0.f, 0.f, 0.f};
    float acc1[4] = {0.f, 0.f, 0.f, 0.f};

    #pragma unroll 4
    for (int kt = 0; kt < 32; ++kt) {
        const int krow = kt * 16 + ln;
        const bf16x8 bfr = *(const bf16x8*)&mlds[swz(krow, q)];
        const float a2v = a2s[krow];
        f32x4 c; c[0] = a2v; c[1] = a2v; c[2] = a2v; c[3] = a2v;
        // D = (x*log2e)·means^T + a2  ->  directly the exp2 argument.
        f32x4 d0 = __builtin_amdgcn_mfma_f32_16x16x32_bf16(a0, bfr, c, 0, 0, 0);
        f32x4 d1 = __builtin_amdgcn_mfma_f32_16x16x32_bf16(a1, bfr, c, 0, 0, 0);
        #pragma unroll
        for (int r = 0; r < 4; ++r) {
            acc0[r] += EXP2F(d0[r]);
            acc1[r] += EXP2F(d1[r]);
        }
    }

    // ---- reduce over the 16 k-columns held across low-4 lane bits; write ----
    #pragma unroll
    for (int r = 0; r < 4; ++r) {
        float v0 = acc0[r], v1 = acc1[r];
        v0 += __shfl_xor(v0, 1); v0 += __shfl_xor(v0, 2);
        v0 += __shfl_xor(v0, 4); v0 += __shfl_xor(v0, 8);
        v1 += __shfl_xor(v1, 1); v1 += __shfl_xor(v1, 2);
        v1 += __shfl_xor(v1, 4); v1 += __shfl_xor(v1, 8);
        if (ln == 0) {
            const int r0 = rw + q * 4 + r;       // C/D row = quad*4 + reg
            const int r1 = r0 + 16;
            out[(size_t)b * Sc + s0 + r0] =
                0.5f * (x2p[2 * r0] + x2p[2 * r0 + 1]) + LOG_NORM - LN2 * LOG2F(v0);
            out[(size_t)b * Sc + s0 + r1] =
                0.5f * (x2p[2 * r1] + x2p[2 * r1 + 1]) + LOG_NORM - LN2 * LOG2F(v1);
        }
    }
}

extern "C" void kernel_launch(void* const* d_in, const int* in_sizes, int n_in,
                              void* d_out, int out_size, void* d_ws, size_t ws_size,
                              hipStream_t stream) {
    const float* x      = (const float*)d_in[0];
    const float* logits = (const float*)d_in[1];
    const float* means  = (const float*)d_in[2];
    float* out = (float*)d_out;
    (void)in_sizes; (void)n_in; (void)out_size; (void)d_ws; (void)ws_size;

    dim3 grid(Bc * (Sc / ST)), block(256);
    hipLaunchKernelGGL(gm_nll_mfma, grid, block, 0, stream, x, logits, means, out);
}